// Round 4
// baseline (278.936 us; speedup 1.0000x reference)
//
#include <hip/hip_runtime.h>
#include <math.h>

#define NQ    64
#define DIM   256
#define SEQ   128
#define CAP   500000
#define TOPK  5
#define KT    32                  // keys per tile
#define NT    (CAP / KT)          // 15625 exact
#define NBLK  512                 // 2 blocks/CU * 256 CU
#define PB    8                   // per-block per-query candidates
#define NC    (NBLK * PB)         // 4096 candidates per query
#define DELTA 2.0e-3f             // bf16-sim safety margin
#define MAXC  192

typedef short short8v __attribute__((ext_vector_type(8)));
typedef float f32x4   __attribute__((ext_vector_type(4)));

#define LGKM0() do { asm volatile("s_waitcnt lgkmcnt(0)" ::: "memory"); \
                     __builtin_amdgcn_sched_barrier(0); } while (0)
#define BAR()   do { __builtin_amdgcn_s_barrier(); \
                     __builtin_amdgcn_sched_barrier(0); } while (0)

__device__ inline unsigned pkbf(float a, float b) {   // 2x fp32 -> packed bf16 (RNE)
    unsigned ua = __builtin_bit_cast(unsigned, a);
    unsigned ub = __builtin_bit_cast(unsigned, b);
    ua = (ua + 0x7fffu + ((ua >> 16) & 1u)) >> 16;
    ub = (ub + 0x7fffu + ((ub >> 16) & 1u)) >> 16;
    return ua | (ub << 16);
}

// ------- Kernel A1: query partial sums (4 chunks of S) + counts copy --------
__global__ void qmean_part_kernel(const float* __restrict__ query,
                                  const float* __restrict__ ac,
                                  float* __restrict__ qpart,
                                  float* __restrict__ outCnt) {
    int blk = blockIdx.x;          // 256
    int d = threadIdx.x;           // 256
    int b = blk >> 2, ch = blk & 3;
    const float* qb = query + ((size_t)b * SEQ + ch * 32) * DIM;
    float s = 0.f;
    #pragma unroll 4
    for (int t = 0; t < 32; ++t) s += qb[(size_t)t * DIM + d];
    qpart[blk * DIM + d] = s;
    for (int i = blk * 256 + d; i < CAP / 4; i += 256 * 256)
        ((float4*)outCnt)[i] = ((const float4*)ac)[i];
}

// ------- Kernel A2: combine partials, mean, L2 normalize --------------------
__global__ void qmean_norm2_kernel(const float* __restrict__ qpart,
                                   float* __restrict__ qn) {
    int b = blockIdx.x;            // 64
    int d = threadIdx.x;           // 256
    float s = qpart[(b * 4 + 0) * DIM + d] + qpart[(b * 4 + 1) * DIM + d]
            + qpart[(b * 4 + 2) * DIM + d] + qpart[(b * 4 + 3) * DIM + d];
    float m = s * (1.0f / SEQ);
    float ss = m * m;
    #pragma unroll
    for (int off = 32; off > 0; off >>= 1) ss += __shfl_down(ss, off, 64);
    __shared__ float red[4];
    if ((threadIdx.x & 63) == 0) red[threadIdx.x >> 6] = ss;
    __syncthreads();
    float tot = red[0] + red[1] + red[2] + red[3];
    float r = 1.0f / fmaxf(sqrtf(tot), 1e-12f);
    qn[b * DIM + d] = m * r;
}

// ------- Kernel B: pipelined bf16-MFMA sims + per-block top-8 ---------------
// 256 thr (4 waves), 32-key fp32 tile double-buffered in swizzled LDS.
// T14 staging: coalesced 4KB/instr loads issued at tile top, ds_write late.
// Raw s_barrier (no vmcnt drain). B(queries) hoisted to regs as bf16 frags.
// Wave w: kh=w&1 (key half), qh=w>>1 (query half). rk applied post-MFMA.
__global__ __launch_bounds__(256, 2) void sims_mfma_topk(
        const float* __restrict__ keys, const float* __restrict__ qn,
        float* __restrict__ candV, int* __restrict__ candI) {
    __shared__ __align__(16) char kbuf[2][KT * DIM * 4];   // 2 x 32 KB fp32, swizzled
    __shared__ float sims[64][33];                          // 8448 B

    const int tid  = threadIdx.x;
    const int lane = tid & 63;
    const int wave = tid >> 6;
    const int key0 = lane & 15;
    const int g    = lane >> 4;
    const int kh   = wave & 1;
    const int qh   = wave >> 1;

    // ---- hoist B: wave's 32 queries as bf16 frags (64 VGPR), one-time ------
    short8v bq0[8], bq1[8];
    {
        const float* q0 = qn + (qh * 32 + key0) * DIM + g * 8;
        const float* q1 = q0 + 16 * DIM;
        #pragma unroll
        for (int st = 0; st < 8; ++st) {
            float4 a = *(const float4*)(q0 + st * 32);
            float4 b = *(const float4*)(q0 + st * 32 + 4);
            uint4 w;
            w.x = pkbf(a.x, a.y); w.y = pkbf(a.z, a.w);
            w.z = pkbf(b.x, b.y); w.w = pkbf(b.z, b.w);
            bq0[st] = __builtin_bit_cast(short8v, w);
            a = *(const float4*)(q1 + st * 32);
            b = *(const float4*)(q1 + st * 32 + 4);
            w.x = pkbf(a.x, a.y); w.y = pkbf(a.z, a.w);
            w.z = pkbf(b.x, b.y); w.w = pkbf(b.z, b.w);
            bq1[st] = __builtin_bit_cast(short8v, w);
        }
    }

    float tv[PB]; int ti[PB];
    #pragma unroll
    for (int p = 0; p < PB; ++p) { tv[p] = -INFINITY; ti[p] = 0; }

    // ---- staging helpers: coalesced issue (4KB/instr), swizzled ds_write ---
    float4 stg[8];
    auto issue = [&](int tile) {
        const char* src = (const char*)keys + (size_t)tile * (KT * DIM * 4);
        #pragma unroll
        for (int j = 0; j < 8; ++j)
            stg[j] = *(const float4*)(src + j * 4096 + tid * 16);
    };
    auto write_stage = [&](int buf) {
        #pragma unroll
        for (int j = 0; j < 8; ++j) {
            int row = j * 4 + wave;              // wave writes full 1KB rows
            unsigned dst = (unsigned)(row * 1024 + ((lane * 16) ^ ((row & 7) << 4)));
            *(float4*)(kbuf[buf] + dst) = stg[j];
        }
    };

    // ---- prologue: stage first tile ----
    int t = blockIdx.x;
    issue(t);
    write_stage(0);
    LGKM0(); BAR();

    const int rowbase = (kh * 16 + key0) * 1024;
    const unsigned swz = (unsigned)((key0 & 7) << 4);
    int cur = 0;
    while (t < NT) {
        const int tn = t + NBLK;
        const bool hn = (tn < NT);
        if (hn) issue(tn);                        // in flight under full tile

        // ---- fused A-build (ssq + bf16) + MFMA from kbuf[cur] ----
        const char* kc = kbuf[cur];
        float ssq = 0.f;
        f32x4 acc0 = {0.f, 0.f, 0.f, 0.f}, acc1 = {0.f, 0.f, 0.f, 0.f};
        #pragma unroll
        for (int st = 0; st < 8; ++st) {
            unsigned c0 = (unsigned)(st * 128 + g * 32);
            f32x4 ra = *(const f32x4*)(kc + rowbase + (c0 ^ swz));
            f32x4 rb = *(const f32x4*)(kc + rowbase + ((c0 + 16) ^ swz));
            ssq = fmaf(ra[0], ra[0], fmaf(ra[1], ra[1],
                  fmaf(ra[2], ra[2], fmaf(ra[3], ra[3], ssq))));
            ssq = fmaf(rb[0], rb[0], fmaf(rb[1], rb[1],
                  fmaf(rb[2], rb[2], fmaf(rb[3], rb[3], ssq))));
            uint4 w;
            w.x = pkbf(ra[0], ra[1]); w.y = pkbf(ra[2], ra[3]);
            w.z = pkbf(rb[0], rb[1]); w.w = pkbf(rb[2], rb[3]);
            short8v afr = __builtin_bit_cast(short8v, w);
            acc0 = __builtin_amdgcn_mfma_f32_16x16x32_bf16(afr, bq0[st], acc0, 0, 0, 0);
            acc1 = __builtin_amdgcn_mfma_f32_16x16x32_bf16(afr, bq1[st], acc1, 0, 0, 0);
        }
        ssq += __shfl_xor(ssq, 16, 64);
        ssq += __shfl_xor(ssq, 32, 64);
        float rk = rsqrtf(fmaxf(ssq, 1e-24f));

        // ---- scale by key norm, write sims (D: col=l&15=query, row=g*4+r=key) ----
        {
            float rks[4];
            #pragma unroll
            for (int r = 0; r < 4; ++r) rks[r] = __shfl(rk, (g << 2) + r, 64);
            int q0 = qh * 32 + key0;
            int k0 = kh * 16 + (g << 2);
            #pragma unroll
            for (int r = 0; r < 4; ++r) {
                sims[q0][k0 + r]      = acc0[r] * rks[r];
                sims[q0 + 16][k0 + r] = acc1[r] * rks[r];
            }
        }
        LGKM0(); BAR();                            // sims visible (no vmcnt drain)

        // ---- scan: lane = query, wave scans its 8 key slots ----
        #pragma unroll
        for (int j = 0; j < 8; ++j) {
            float v = sims[lane][wave * 8 + j];
            if (v > tv[PB - 1]) {
                tv[PB - 1] = v; ti[PB - 1] = t * KT + wave * 8 + j;
                #pragma unroll
                for (int p = PB - 1; p > 0; --p) {
                    if (tv[p] > tv[p - 1]) {
                        float fv = tv[p]; tv[p] = tv[p - 1]; tv[p - 1] = fv;
                        int   fi = ti[p]; ti[p] = ti[p - 1]; ti[p - 1] = fi;
                    }
                }
            }
        }
        if (hn) write_stage(cur ^ 1);              // compiler waits stg vmcnt here
        LGKM0(); BAR();                            // staged buffer visible
        cur ^= 1; t = tn;
    }

    // ---- block merge: 4 wave-lists (disjoint key slots) -> top-8/query ----
    float* mv = (float*)&kbuf[0][0];
    int*   mi = (int*)&kbuf[0][0] + 2048;
    {
        int base = (wave * 64 + lane) * PB;
        #pragma unroll
        for (int p = 0; p < PB; ++p) { mv[base + p] = tv[p]; mi[base + p] = ti[p]; }
    }
    __syncthreads();
    if (wave == 0) {
        float fv[PB]; int fi[PB];
        #pragma unroll
        for (int p = 0; p < PB; ++p) { fv[p] = -INFINITY; fi[p] = 0; }
        for (int w = 0; w < 4; ++w) {
            #pragma unroll
            for (int p = 0; p < PB; ++p) {
                float v = mv[(w * 64 + lane) * PB + p];
                int  id = mi[(w * 64 + lane) * PB + p];
                if (v > fv[PB - 1]) {
                    fv[PB - 1] = v; fi[PB - 1] = id;
                    #pragma unroll
                    for (int p2 = PB - 1; p2 > 0; --p2) {
                        if (fv[p2] > fv[p2 - 1]) {
                            float a = fv[p2]; fv[p2] = fv[p2 - 1]; fv[p2 - 1] = a;
                            int   c = fi[p2]; fi[p2] = fi[p2 - 1]; fi[p2 - 1] = c;
                        }
                    }
                }
            }
        }
        size_t cb = ((size_t)lane * NBLK + blockIdx.x) * PB;
        #pragma unroll
        for (int p = 0; p < PB; ++p) { candV[cb + p] = fv[p]; candI[cb + p] = fi[p]; }
    }
}

// ---- Kernel C: global bf16-top5 -> threshold select -> exact fp32 rescore ----
__global__ void finalize_kernel(const float* __restrict__ candV,
                                const int* __restrict__ candI,
                                const float* __restrict__ keys,
                                const float* __restrict__ qn,
                                const float* __restrict__ values,
                                float* __restrict__ outRet,
                                float* __restrict__ outCnt) {
    const int b = blockIdx.x;      // query
    const int t = threadIdx.x;     // 256
    const int lane = t & 63, wave = t >> 6;
    __shared__ float rv[256]; __shared__ int rp[256];
    __shared__ int   chosen[TOPK];
    __shared__ float v5s;
    __shared__ int   clist[MAXC];
    __shared__ float rsc[MAXC];
    __shared__ int   ccnt;
    __shared__ float qs[DIM];
    __shared__ int   kidx[TOPK];

    const float* cv = candV + (size_t)b * NC;
    const int*   ci = candI + (size_t)b * NC;

    for (int pass = 0; pass < TOPK; ++pass) {
        float lv = -INFINITY; int lp = 0x7fffffff;
        for (int m = t; m < NC; m += 256) {
            bool skip = false;
            for (int k2 = 0; k2 < pass; ++k2) skip |= (m == chosen[k2]);
            float v = cv[m];
            if (!skip && (v > lv || (v == lv && m < lp))) { lv = v; lp = m; }
        }
        rv[t] = lv; rp[t] = lp;
        __syncthreads();
        for (int s = 128; s > 0; s >>= 1) {
            if (t < s) {
                if (rv[t + s] > rv[t] || (rv[t + s] == rv[t] && rp[t + s] < rp[t])) {
                    rv[t] = rv[t + s]; rp[t] = rp[t + s];
                }
            }
            __syncthreads();
        }
        if (t == 0) { chosen[pass] = rp[0]; if (pass == TOPK - 1) v5s = rv[0]; }
        __syncthreads();
    }

    if (t == 0) ccnt = 0;
    __syncthreads();
    float thr = v5s - DELTA;
    for (int m = t; m < NC; m += 256) {
        if (cv[m] >= thr) {
            int pos = atomicAdd(&ccnt, 1);
            if (pos < MAXC) clist[pos] = ci[m];
        }
    }
    qs[t] = qn[b * DIM + t];
    __syncthreads();
    int cnt = min(ccnt, MAXC);

    for (int c = wave; c < cnt; c += 4) {
        const float4 k4 = *(const float4*)(keys + (size_t)clist[c] * DIM + lane * 4);
        const float4 q4 = *(const float4*)(qs + lane * 4);
        float d  = q4.x * k4.x + q4.y * k4.y + q4.z * k4.z + q4.w * k4.w;
        float s2 = k4.x * k4.x + k4.y * k4.y + k4.z * k4.z + k4.w * k4.w;
        #pragma unroll
        for (int off = 1; off < 64; off <<= 1) {
            d  += __shfl_xor(d, off, 64);
            s2 += __shfl_xor(s2, off, 64);
        }
        if (lane == 0) rsc[c] = d * rsqrtf(fmaxf(s2, 1e-24f));
    }
    __syncthreads();

    for (int pass = 0; pass < TOPK; ++pass) {
        float lv = -INFINITY; int lp = 0x7fffffff;
        if (t < cnt) {
            bool skip = false;
            for (int k2 = 0; k2 < pass; ++k2) skip |= (t == chosen[k2]);
            if (!skip) { lv = rsc[t]; lp = t; }
        }
        rv[t] = lv; rp[t] = lp;
        __syncthreads();
        for (int s = 128; s > 0; s >>= 1) {
            if (t < s) {
                if (rv[t + s] > rv[t] || (rv[t + s] == rv[t] && rp[t + s] < rp[t])) {
                    rv[t] = rv[t + s]; rp[t] = rp[t + s];
                }
            }
            __syncthreads();
        }
        if (t == 0) { chosen[pass] = rp[0]; kidx[pass] = clist[rp[0]]; }
        __syncthreads();
    }

    float s = 0.f;
    #pragma unroll
    for (int p = 0; p < TOPK; ++p) s += values[(size_t)kidx[p] * DIM + t];
    outRet[b * DIM + t] = s * 0.2f;
    if (t < TOPK) atomicAdd(&outCnt[kidx[t]], 1.0f);
}

// ---------------- launch -----------------------------------------------------
extern "C" void kernel_launch(void* const* d_in, const int* in_sizes, int n_in,
                              void* d_out, int out_size, void* d_ws, size_t ws_size,
                              hipStream_t stream) {
    const float* query  = (const float*)d_in[0];
    const float* keys   = (const float*)d_in[1];
    const float* values = (const float*)d_in[2];
    const float* acnt   = (const float*)d_in[3];
    float* outRet = (float*)d_out;
    float* outCnt = outRet + NQ * DIM;

    char* ws = (char*)d_ws;
    float* qn    = (float*)ws;                                   // 64 KB
    float* qpart = (float*)(ws + 65536);                         // 256 KB
    float* candV = (float*)(ws + 65536 + 262144);                // 1 MB
    int*   candI = (int*)(ws + 65536 + 262144 + (size_t)NQ * NC * 4);

    qmean_part_kernel<<<256, 256, 0, stream>>>(query, acnt, qpart, outCnt);
    qmean_norm2_kernel<<<NQ, 256, 0, stream>>>(qpart, qn);
    sims_mfma_topk<<<NBLK, 256, 0, stream>>>(keys, qn, candV, candI);
    finalize_kernel<<<NQ, 256, 0, stream>>>(candV, candI, keys, qn, values,
                                            outRet, outCnt);
}